// Round 3
// baseline (181.713 us; speedup 1.0000x reference)
//
#include <hip/hip_runtime.h>
#include <hip/hip_bf16.h>

#define IN_F   4096
#define OUT_F  4096
#define QBLK   8
#define NBLKS  512
#define NTOK   1024
#define NCENT  2048
#define SPLITK 4

typedef unsigned int u32;
typedef unsigned short u16;
typedef __attribute__((ext_vector_type(8)))  short short8;    // 8 bf16 (MFMA A/B frag)
typedef __attribute__((ext_vector_type(16))) float floatx16;  // 32x32 MFMA C/D frag

// round-to-nearest-even fp32 -> bf16
__device__ __forceinline__ u16 f2bf(float f) {
  union { float f; u32 u; } v; v.f = f;
  u32 u = v.u;
  return (u16)((u + 0x7fffu + ((u >> 16) & 1u)) >> 16);
}

__device__ __forceinline__ void load_lds_16(const void* g, void* l) {
  __builtin_amdgcn_global_load_lds(
      (const __attribute__((address_space(1))) u32*)g,
      (__attribute__((address_space(3))) u32*)l, 16, 0, 0);
}

// ---------------------------------------------------------------------------
// Prep: cast x->bf16, cast centroids->bf16, init out = bias (for atomic GEMM).
// 2048 blocks x 256 threads; each thread: one 8-elem x chunk, two float4 of
// out-init; first 2048 threads also cast the centroid table.
// ---------------------------------------------------------------------------
__global__ __launch_bounds__(256) void prep_kernel(
    const float* __restrict__ x, const float* __restrict__ cent,
    const float* __restrict__ bias,
    u16* __restrict__ xb, u16* __restrict__ centb, float* __restrict__ out) {
  const int g = blockIdx.x * 256 + threadIdx.x;   // 0 .. 512K-1

  // cast x chunk g (8 fp32 -> 8 bf16)
  {
    const float4* xv = (const float4*)x;
    float4 a = xv[(size_t)g * 2];
    float4 b = xv[(size_t)g * 2 + 1];
    union { u16 s[8]; uint4 v; } o;
    o.s[0] = f2bf(a.x); o.s[1] = f2bf(a.y); o.s[2] = f2bf(a.z); o.s[3] = f2bf(a.w);
    o.s[4] = f2bf(b.x); o.s[5] = f2bf(b.y); o.s[6] = f2bf(b.z); o.s[7] = f2bf(b.w);
    ((uint4*)xb)[g] = o.v;
  }

  // out init: float4 indices 2g, 2g+1; bias4[f & 1023] broadcasts per row
  {
    const float4* b4 = (const float4*)bias;
    float4* o4 = (float4*)out;
    o4[(size_t)g * 2]     = b4[(2 * g) & 1023];
    o4[(size_t)g * 2 + 1] = b4[(2 * g + 1) & 1023];
  }

  // cast centroid table (2048 chunks of 8)
  if (g < NCENT) {
    const float4* cv = (const float4*)cent;
    float4 a = cv[(size_t)g * 2];
    float4 b = cv[(size_t)g * 2 + 1];
    union { u16 s[8]; uint4 v; } o;
    o.s[0] = f2bf(a.x); o.s[1] = f2bf(a.y); o.s[2] = f2bf(a.z); o.s[3] = f2bf(a.w);
    o.s[4] = f2bf(b.x); o.s[5] = f2bf(b.y); o.s[6] = f2bf(b.z); o.s[7] = f2bf(b.w);
    ((uint4*)centb)[g] = o.v;
  }
}

// ---------------------------------------------------------------------------
// Barrier-free fused GEMM.
// C[m][n] += sum_k x[m][k] * centroids[assign[(k/8)*OUT_F+n]][k%8]
// Block 128x128, 4 waves (2x2), wave tile 64x64 = 2x2 of mfma_f32_32x32x16_bf16.
// A frags: direct global loads from bf16 xb (no LDS staging, no K-loop
// barriers). B frags: gathered from 32KB bf16 centroid table in LDS; for
// 32x32x16 each half-wave's k-range is exactly one 8-wide quant block, so one
// 16B LDS lookup per lane. idx loads are 128B-coalesced per half-wave.
// Split-K over gridDim.z; epilogue atomically accumulates into out (pre-set
// to bias by prep_kernel).
// ---------------------------------------------------------------------------
__global__ __launch_bounds__(256, 4) void gemm_fused2_kernel(
    const u16* __restrict__ A,      // xb [NTOK][IN_F] bf16
    const u16* __restrict__ centb,  // [NCENT][8] bf16
    const int* __restrict__ assign, // [NBLKS*OUT_F] block-major
    float* __restrict__ out) {      // [NTOK][OUT_F], pre-initialized to bias
  __shared__ __align__(16) u16 cs[NCENT * 8];   // 32 KB

  const int t = threadIdx.x;
  const int lane = t & 63;
  const int wv = t >> 6;
  const int wm = wv >> 1;
  const int wn = wv & 1;
  const int l31 = lane & 31;
  const int half = lane >> 5;
  const int m0 = blockIdx.y * 128;
  const int n0 = blockIdx.x * 128;
  const int k_base = blockIdx.z * (IN_F / SPLITK);   // 1024-wide K chunk
  const int NK = (IN_F / SPLITK) / 16;               // 64 k-steps of 16

  // stage centroid table: 2048 x 16B chunks, 8 per thread (DMA)
#pragma unroll
  for (int it = 0; it < 8; ++it) {
    int c = it * 256 + t;
    load_lds_16(centb + (size_t)c * 8, cs + (size_t)c * 8);
  }

  floatx16 acc[2][2];
#pragma unroll
  for (int i = 0; i < 2; ++i)
#pragma unroll
    for (int j = 0; j < 2; ++j)
#pragma unroll
      for (int r = 0; r < 16; ++r) acc[i][j][r] = 0.0f;

  // A: lane reads m = m0 + wm*64 + jm*32 + l31, k = k_base + ks*16 + half*8
  const u16* ap0 = A + (size_t)(m0 + wm * 64 + l31) * IN_F + k_base + half * 8;
  const u16* ap1 = ap0 + 32 * IN_F;
  // idx: assign[(k_base/8 + ks*2 + half)*OUT_F + n0 + wn*64 + jn*32 + l31]
  const int* ip0 = assign + (size_t)((k_base >> 3) + half) * OUT_F + n0 + wn * 64 + l31;
  const int* ip1 = ip0 + 32;

  __syncthreads();   // cs DMA drained (syncthreads waits vmcnt) + all waves see it

  const short8* csv = (const short8*)cs;

  short8 a0 = *(const short8*)ap0;
  short8 a1 = *(const short8*)ap1;
  int i0 = *ip0, i1 = *ip1;

#pragma unroll 4
  for (int ks = 0; ks < NK - 1; ++ks) {
    short8 b0 = csv[i0];
    short8 b1 = csv[i1];
    // prefetch next iteration's A frags and indices
    ap0 += 16; ap1 += 16;
    ip0 += 2 * OUT_F; ip1 += 2 * OUT_F;
    short8 na0 = *(const short8*)ap0;
    short8 na1 = *(const short8*)ap1;
    int ni0 = *ip0, ni1 = *ip1;

    acc[0][0] = __builtin_amdgcn_mfma_f32_32x32x16_bf16(a0, b0, acc[0][0], 0, 0, 0);
    acc[0][1] = __builtin_amdgcn_mfma_f32_32x32x16_bf16(a0, b1, acc[0][1], 0, 0, 0);
    acc[1][0] = __builtin_amdgcn_mfma_f32_32x32x16_bf16(a1, b0, acc[1][0], 0, 0, 0);
    acc[1][1] = __builtin_amdgcn_mfma_f32_32x32x16_bf16(a1, b1, acc[1][1], 0, 0, 0);

    a0 = na0; a1 = na1; i0 = ni0; i1 = ni1;
  }
  {
    short8 b0 = csv[i0];
    short8 b1 = csv[i1];
    acc[0][0] = __builtin_amdgcn_mfma_f32_32x32x16_bf16(a0, b0, acc[0][0], 0, 0, 0);
    acc[0][1] = __builtin_amdgcn_mfma_f32_32x32x16_bf16(a0, b1, acc[0][1], 0, 0, 0);
    acc[1][0] = __builtin_amdgcn_mfma_f32_32x32x16_bf16(a1, b0, acc[1][0], 0, 0, 0);
    acc[1][1] = __builtin_amdgcn_mfma_f32_32x32x16_bf16(a1, b1, acc[1][1], 0, 0, 0);
  }

  // epilogue: 32x32 C/D layout col = lane&31, row = (r&3) + 8*(r>>2) + 4*half
#pragma unroll
  for (int jm = 0; jm < 2; ++jm) {
#pragma unroll
    for (int jn = 0; jn < 2; ++jn) {
      const int col = n0 + wn * 64 + jn * 32 + l31;
      const int rbase = m0 + wm * 64 + jm * 32 + 4 * half;
#pragma unroll
      for (int r = 0; r < 16; ++r) {
        const int row = rbase + (r & 3) + 8 * (r >> 2);
        unsafeAtomicAdd(&out[(size_t)row * OUT_F + col], acc[jm][jn][r]);
      }
    }
  }
}

extern "C" void kernel_launch(void* const* d_in, const int* in_sizes, int n_in,
                              void* d_out, int out_size, void* d_ws, size_t ws_size,
                              hipStream_t stream) {
  const float* x      = (const float*)d_in[0];  // [1024][4096] fp32
  const float* cent   = (const float*)d_in[1];  // [2048][8] fp32
  const float* bias   = (const float*)d_in[2];  // [4096] fp32
  const int*   assign = (const int*)d_in[3];    // [512*4096] int32
  float* out = (float*)d_out;

  // ws layout: xb (8 MB) | centb (32 KB)
  u16* xb    = (u16*)d_ws;
  u16* centb = (u16*)((char*)d_ws + (size_t)NTOK * IN_F * sizeof(u16));

  hipLaunchKernelGGL(prep_kernel, dim3((NTOK * IN_F / 8) / 256), dim3(256), 0, stream,
                     x, cent, bias, xb, centb, out);
  hipLaunchKernelGGL(gemm_fused2_kernel, dim3(OUT_F / 128, NTOK / 128, SPLITK), dim3(256), 0, stream,
                     xb, centb, assign, out);
}

// Round 4
// 157.230 us; speedup vs baseline: 1.1557x; 1.1557x over previous
//
#include <hip/hip_runtime.h>
#include <hip/hip_bf16.h>

#define IN_F   4096
#define OUT_F  4096
#define QBLK   8
#define NBLKS  512
#define NTOK   1024
#define NCENT  2048
#define SPLITK 4

typedef unsigned int u32;
typedef unsigned short u16;
typedef __attribute__((ext_vector_type(8)))  short short8;    // 8 bf16 (MFMA A/B frag)
typedef __attribute__((ext_vector_type(16))) float floatx16;  // 32x32 MFMA C/D frag

// round-to-nearest-even fp32 -> bf16
__device__ __forceinline__ u16 f2bf(float f) {
  union { float f; u32 u; } v; v.f = f;
  u32 u = v.u;
  return (u16)((u + 0x7fffu + ((u >> 16) & 1u)) >> 16);
}

__device__ __forceinline__ void load_lds_16(const void* g, void* l) {
  __builtin_amdgcn_global_load_lds(
      (const __attribute__((address_space(1))) u32*)g,
      (__attribute__((address_space(3))) u32*)l, 16, 0, 0);
}

// ---------------------------------------------------------------------------
// Prep: cast x->bf16, cast centroids->bf16, init out = bias (for atomic GEMM).
// ---------------------------------------------------------------------------
__global__ __launch_bounds__(256) void prep_kernel(
    const float* __restrict__ x, const float* __restrict__ cent,
    const float* __restrict__ bias,
    u16* __restrict__ xb, u16* __restrict__ centb, float* __restrict__ out) {
  const int g = blockIdx.x * 256 + threadIdx.x;   // 0 .. 512K-1

  {
    const float4* xv = (const float4*)x;
    float4 a = xv[(size_t)g * 2];
    float4 b = xv[(size_t)g * 2 + 1];
    union { u16 s[8]; uint4 v; } o;
    o.s[0] = f2bf(a.x); o.s[1] = f2bf(a.y); o.s[2] = f2bf(a.z); o.s[3] = f2bf(a.w);
    o.s[4] = f2bf(b.x); o.s[5] = f2bf(b.y); o.s[6] = f2bf(b.z); o.s[7] = f2bf(b.w);
    ((uint4*)xb)[g] = o.v;
  }
  {
    const float4* b4 = (const float4*)bias;
    float4* o4 = (float4*)out;
    o4[(size_t)g * 2]     = b4[(2 * g) & 1023];
    o4[(size_t)g * 2 + 1] = b4[(2 * g + 1) & 1023];
  }
  if (g < NCENT) {
    const float4* cv = (const float4*)cent;
    float4 a = cv[(size_t)g * 2];
    float4 b = cv[(size_t)g * 2 + 1];
    union { u16 s[8]; uint4 v; } o;
    o.s[0] = f2bf(a.x); o.s[1] = f2bf(a.y); o.s[2] = f2bf(a.z); o.s[3] = f2bf(a.w);
    o.s[4] = f2bf(b.x); o.s[5] = f2bf(b.y); o.s[6] = f2bf(b.z); o.s[7] = f2bf(b.w);
    ((uint4*)centb)[g] = o.v;
  }
}

// ---------------------------------------------------------------------------
// Fused GEMM, staged-A + LDS centroid-table gathers, 32x32x16 MFMA.
// C[m][n] += sum_k x[m][k] * centroids[assign[(k/8)*OUT_F+n]][k%8]
// Block 128x128, 4 waves (2x2), wave tile 64x64 = 2x2 of 32x32 frags.
// A: DMA-staged into 8KB LDS per BK=32, XOR swizzle chunk^((row>>1)&3)
//    (covers all 32 banks over 8 rows -> conflict-free frag reads; swizzle
//    applied on the GLOBAL address since DMA forces linear LDS placement).
// B: one 16B LDS gather per 32-col frag per 8-k quant block; idx prefetched
//    one kt ahead into registers (hides global latency across a full kt).
// Split-K=4 over gridDim.z; atomic accumulate into bias-pre-set out.
// ---------------------------------------------------------------------------
__global__ __launch_bounds__(256, 4) void gemm_fused3_kernel(
    const u16* __restrict__ A,      // xb [NTOK][IN_F] bf16
    const u16* __restrict__ centb,  // [NCENT][8] bf16
    const int* __restrict__ assign, // [NBLKS*OUT_F] block-major
    float* __restrict__ out) {      // [NTOK][OUT_F], pre-initialized to bias
  __shared__ __align__(16) u16 cs[NCENT * 8];   // 32 KB
  __shared__ __align__(16) u16 As[128 * 32];    // 8 KB
  const int NKT = (IN_F / SPLITK) / 32;         // 32 kt iterations

  const int t = threadIdx.x;
  const int lane = t & 63;
  const int wv = t >> 6;
  const int wm = wv >> 1;
  const int wn = wv & 1;
  const int l31 = lane & 31;
  const int half = lane >> 5;
  const int m0 = blockIdx.y * 128;
  const int n0 = blockIdx.x * 128;
  const int k_base = blockIdx.z * (IN_F / SPLITK);

  // stage centroid table: 2048 x 16B chunks, 8 per thread (DMA)
#pragma unroll
  for (int it = 0; it < 8; ++it) {
    int c = it * 256 + t;
    load_lds_16(centb + (size_t)c * 8, cs + (size_t)c * 8);
  }

  floatx16 acc[2][2];
#pragma unroll
  for (int i = 0; i < 2; ++i)
#pragma unroll
    for (int j = 0; j < 2; ++j)
#pragma unroll
      for (int r = 0; r < 16; ++r) acc[i][j][r] = 0.0f;

  // idx base: entry for (kt, s, j) = ip[(kt*4 + s*2)*OUT_F + j*32]
  const int* ip = assign + (size_t)((k_base >> 3) + half) * OUT_F + n0 + wn * 64 + l31;
  // A staging: chunk p -> row p>>2, logical chunk (p&3); global side swizzled
  const int arow = t >> 2;                         // staging row for this thread
  const u16* ag0 = A + (size_t)(m0 + arow) * IN_F + k_base + (((t & 3) ^ ((arow >> 1) & 3)) * 8);
  const int arow1 = (256 + t) >> 2;
  const u16* ag1 = A + (size_t)(m0 + arow1) * IN_F + k_base + (((t & 3) ^ ((arow1 >> 1) & 3)) * 8);
  const int sw = (l31 >> 1) & 3;                   // read-side swizzle

  // prefetch idx for kt=0
  int id[2][2];
#pragma unroll
  for (int s = 0; s < 2; ++s)
#pragma unroll
    for (int j = 0; j < 2; ++j)
      id[s][j] = ip[(size_t)(s * 2) * OUT_F + j * 32];

  const short8* csv = (const short8*)cs;
  const short8* Asv = (const short8*)As;
  const int abase0 = (wm * 64 + l31) * 4;          // jm=0 row base (x16B chunks)
  const int abase1 = (wm * 64 + 32 + l31) * 4;     // jm=1

  for (int kt = 0; kt < NKT; ++kt) {
    // stage A tile for this kt (2 DMA chunks per thread)
    load_lds_16(ag0 + kt * 32, &As[t * 8]);
    load_lds_16(ag1 + kt * 32, &As[(256 + t) * 8]);
    __syncthreads();   // drains DMA (incl. cs on kt=0)

    // prefetch idx for kt+1 (clamped re-read on last iter; avoids OOB)
    const int ktn = (kt + 1 < NKT) ? (kt + 1) : kt;
    int nid[2][2];
#pragma unroll
    for (int s = 0; s < 2; ++s)
#pragma unroll
      for (int j = 0; j < 2; ++j)
        nid[s][j] = ip[(size_t)(ktn * 4 + s * 2) * OUT_F + j * 32];

#pragma unroll
    for (int s = 0; s < 2; ++s) {
      short8 b0 = csv[id[s][0]];
      short8 b1 = csv[id[s][1]];
      short8 a0 = Asv[abase0 + ((s * 2 + half) ^ sw)];
      short8 a1 = Asv[abase1 + ((s * 2 + half) ^ sw)];
      acc[0][0] = __builtin_amdgcn_mfma_f32_32x32x16_bf16(a0, b0, acc[0][0], 0, 0, 0);
      acc[0][1] = __builtin_amdgcn_mfma_f32_32x32x16_bf16(a0, b1, acc[0][1], 0, 0, 0);
      acc[1][0] = __builtin_amdgcn_mfma_f32_32x32x16_bf16(a1, b0, acc[1][0], 0, 0, 0);
      acc[1][1] = __builtin_amdgcn_mfma_f32_32x32x16_bf16(a1, b1, acc[1][1], 0, 0, 0);
    }

#pragma unroll
    for (int s = 0; s < 2; ++s)
#pragma unroll
      for (int j = 0; j < 2; ++j)
        id[s][j] = nid[s][j];

    __syncthreads();   // protect As from next iteration's staging
  }

  // epilogue: 32x32 C/D layout col = lane&31, row = (r&3) + 8*(r>>2) + 4*half
#pragma unroll
  for (int jm = 0; jm < 2; ++jm) {
#pragma unroll
    for (int jn = 0; jn < 2; ++jn) {
      const int col = n0 + wn * 64 + jn * 32 + l31;
      const int rbase = m0 + wm * 64 + jm * 32 + 4 * half;
#pragma unroll
      for (int r = 0; r < 16; ++r) {
        const int row = rbase + (r & 3) + 8 * (r >> 2);
        unsafeAtomicAdd(&out[(size_t)row * OUT_F + col], acc[jm][jn][r]);
      }
    }
  }
}

extern "C" void kernel_launch(void* const* d_in, const int* in_sizes, int n_in,
                              void* d_out, int out_size, void* d_ws, size_t ws_size,
                              hipStream_t stream) {
  const float* x      = (const float*)d_in[0];  // [1024][4096] fp32
  const float* cent   = (const float*)d_in[1];  // [2048][8] fp32
  const float* bias   = (const float*)d_in[2];  // [4096] fp32
  const int*   assign = (const int*)d_in[3];    // [512*4096] int32
  float* out = (float*)d_out;

  // ws layout: xb (8 MB) | centb (32 KB)
  u16* xb    = (u16*)d_ws;
  u16* centb = (u16*)((char*)d_ws + (size_t)NTOK * IN_F * sizeof(u16));

  hipLaunchKernelGGL(prep_kernel, dim3((NTOK * IN_F / 8) / 256), dim3(256), 0, stream,
                     x, cent, bias, xb, centb, out);
  hipLaunchKernelGGL(gemm_fused3_kernel, dim3(OUT_F / 128, NTOK / 128, SPLITK), dim3(256), 0, stream,
                     xb, centb, assign, out);
}